// Round 13
// baseline (192.207 us; speedup 1.0000x reference)
//
#include <hip/hip_runtime.h>
#include <hip/hip_bf16.h>
#include <math.h>

#define T_LEN 4096
#define C_DIM 768
#define H_NUM 12
#define D_DIM 64

typedef __bf16 bf16x8 __attribute__((ext_vector_type(8)));
typedef float f32x16 __attribute__((ext_vector_type(16)));

#define LOG2E 1.4426950408889634f

static __device__ __forceinline__ unsigned short bf16bits(float f) {
    return __builtin_bit_cast(unsigned short, __float2bfloat16(f));
}

template <typename TP>
static __device__ __forceinline__ void stp(TP* p, float v) {
    if constexpr (sizeof(TP) == 4) *p = v;
    else *p = __float2bfloat16(v);
}
template <typename TP>
static __device__ __forceinline__ float ldp(const TP* p) {
    if constexpr (sizeof(TP) == 4) return *p;
    else return __bfloat162float(*p);
}

// ---------------------------------------------------------------------------
// Fused prep: blocks 0..767 = vtx (Vt + xhi/xlo split), 768..1055 = Wt.
// ---------------------------------------------------------------------------
__global__ __launch_bounds__(256) void prep_kernel(
    const float* __restrict__ x,
    const float* __restrict__ Wk, const float* __restrict__ Wq,
    __hip_bfloat16* __restrict__ Vt,
    __hip_bfloat16* __restrict__ xhi,
    __hip_bfloat16* __restrict__ xlo,
    __hip_bfloat16* __restrict__ wt) {
    __shared__ float tile[64][65];
    const int bx = blockIdx.x;
    const int tid = threadIdx.x;
    const int cl = tid & 63;
    const int rq = tid >> 6;
    if (bx < 768) {
        const int t0 = (bx & 63) * 64;
        const int c0 = (bx >> 6) * 64;
#pragma unroll
        for (int rr = 0; rr < 16; ++rr) {
            const int row = rr * 4 + rq;
            const float v = x[(size_t)(t0 + row) * C_DIM + c0 + cl];
            tile[row][cl] = v;
            const __hip_bfloat16 hb = __float2bfloat16(v);
            xhi[(size_t)(t0 + row) * C_DIM + c0 + cl] = hb;
            xlo[(size_t)(t0 + row) * C_DIM + c0 + cl] =
                __float2bfloat16(v - __bfloat162float(hb));
        }
        __syncthreads();
#pragma unroll
        for (int cc = 0; cc < 16; ++cc) {
            const int c = cc * 4 + rq;
            const int gc = c0 + c;
            const int h = gc >> 6, d = gc & 63;
            Vt[((size_t)h * D_DIM + d) * T_LEN + t0 + cl] =
                __float2bfloat16(tile[cl][c]);
        }
    } else {
        const int bz = bx - 768;               // 0..287
        const int w  = bz / 144;
        const int rem = bz - w * 144;
        const int k0 = (rem % 12) * 64;
        const int n0 = (rem / 12) * 64;
        const float* W = w ? Wq : Wk;
        __hip_bfloat16* o = wt + (size_t)w * C_DIM * C_DIM;
#pragma unroll
        for (int rr = 0; rr < 16; ++rr) {
            const int row = rr * 4 + rq;
            tile[row][cl] = W[(size_t)(k0 + row) * C_DIM + n0 + cl];
        }
        __syncthreads();
#pragma unroll
        for (int rr = 0; rr < 16; ++rr) {
            const int row = rr * 4 + rq;       // n within tile
            o[(size_t)(n0 + row) * C_DIM + k0 + cl] =
                __float2bfloat16(tile[cl][row]);
        }
    }
}

// ---------------------------------------------------------------------------
// LDS-staged projection GEMM (validated round 11). K output scaled by log2e
// so attention can use native exp2.
// ---------------------------------------------------------------------------
__global__ __launch_bounds__(256) void proj_mfma2(
    const __hip_bfloat16* __restrict__ xhi,
    const __hip_bfloat16* __restrict__ xlo,
    const __hip_bfloat16* __restrict__ wt,
    const float* __restrict__ bk, const float* __restrict__ bq,
    __hip_bfloat16* __restrict__ kout, __hip_bfloat16* __restrict__ qout) {

    __shared__ __align__(16) char AhiL[16384];
    __shared__ __align__(16) char AloL[16384];
    __shared__ __align__(16) char BL[8192];

    const int bid = blockIdx.x;                   // 768 = 8 x 96
    const int wg  = (bid & 7) * 96 + (bid >> 3);  // XCD chunk swizzle
    const int mt  = wg / 24;
    const int nc  = wg - mt * 24;
    const int wsel = nc / 12;
    const int nt  = nc - wsel * 12;
    const int m0 = mt * 128, n0 = nt * 64;

    const int tid = threadIdx.x;
    const int wv = tid >> 6;
    const int lane = tid & 63;
    const int lm = lane & 31, hi = lane >> 5;

    const __hip_bfloat16* wb = wt + (size_t)wsel * C_DIM * C_DIM;

    f32x16 acc0 = {}, acc1 = {};
    const int arow = wv * 32 + lm;
    const int asw = arow & 7;
    const int bsw = lm & 7;

    for (int k0 = 0; k0 < C_DIM; k0 += 64) {
        __syncthreads();
#pragma unroll
        for (int it = 0; it < 4; ++it) {
            const int g = tid + it * 256;
            const int row = g >> 3, ch = g & 7;
            const int dst = row * 128 + ((ch ^ (row & 7)) << 4);
            *reinterpret_cast<uint4*>(AhiL + dst) =
                *reinterpret_cast<const uint4*>(
                    xhi + (size_t)(m0 + row) * C_DIM + k0 + ch * 8);
            *reinterpret_cast<uint4*>(AloL + dst) =
                *reinterpret_cast<const uint4*>(
                    xlo + (size_t)(m0 + row) * C_DIM + k0 + ch * 8);
        }
#pragma unroll
        for (int it = 0; it < 2; ++it) {
            const int g = tid + it * 256;
            const int row = g >> 3, ch = g & 7;
            const int dst = row * 128 + ((ch ^ (row & 7)) << 4);
            *reinterpret_cast<uint4*>(BL + dst) =
                *reinterpret_cast<const uint4*>(
                    wb + (size_t)(n0 + row) * C_DIM + k0 + ch * 8);
        }
        __syncthreads();

#pragma unroll
        for (int ki = 0; ki < 4; ++ki) {
            const int ch = ki * 2 + hi;
            const bf16x8 ah = *reinterpret_cast<const bf16x8*>(
                AhiL + arow * 128 + ((ch ^ asw) << 4));
            const bf16x8 al = *reinterpret_cast<const bf16x8*>(
                AloL + arow * 128 + ((ch ^ asw) << 4));
            const bf16x8 b0 = *reinterpret_cast<const bf16x8*>(
                BL + lm * 128 + ((ch ^ bsw) << 4));
            const bf16x8 b1 = *reinterpret_cast<const bf16x8*>(
                BL + (32 + lm) * 128 + ((ch ^ bsw) << 4));
            acc0 = __builtin_amdgcn_mfma_f32_32x32x16_bf16(ah, b0, acc0, 0, 0, 0);
            acc1 = __builtin_amdgcn_mfma_f32_32x32x16_bf16(ah, b1, acc1, 0, 0, 0);
            acc0 = __builtin_amdgcn_mfma_f32_32x32x16_bf16(al, b0, acc0, 0, 0, 0);
            acc1 = __builtin_amdgcn_mfma_f32_32x32x16_bf16(al, b1, acc1, 0, 0, 0);
        }
    }

    const float* bias = wsel ? bq : bk;
    __hip_bfloat16* out = wsel ? qout : kout;
    const float kscale = wsel ? 1.0f : LOG2E;   // K carries log2e for exp2 softmax
    const int h = nt;
    const float bv0 = bias[n0 + lm];
    const float bv1 = bias[n0 + 32 + lm];
#pragma unroll
    for (int r = 0; r < 16; ++r) {
        const int cr = (r & 3) + 8 * (r >> 2) + 4 * hi;
        const int t = m0 + wv * 32 + cr;
        out[((size_t)h * T_LEN + t) * D_DIM + lm]      = __float2bfloat16((acc0[r] + bv0) * kscale);
        out[((size_t)h * T_LEN + t) * D_DIM + 32 + lm] = __float2bfloat16((acc1[r] + bv1) * kscale);
    }
}

// ---------------------------------------------------------------------------
// Fallback prep + fp32 projection (K scaled by log2e) — only if ws is tiny.
// ---------------------------------------------------------------------------
__global__ __launch_bounds__(256) void vtx_only_kernel(
    const float* __restrict__ x, __hip_bfloat16* __restrict__ Vt) {
    __shared__ float tile[64][65];
    const int t0 = blockIdx.x * 64;
    const int c0 = blockIdx.y * 64;
    const int tid = threadIdx.x;
    const int cl = tid & 63;
    const int rq = tid >> 6;
#pragma unroll
    for (int rr = 0; rr < 16; ++rr) {
        const int row = rr * 4 + rq;
        tile[row][cl] = x[(size_t)(t0 + row) * C_DIM + c0 + cl];
    }
    __syncthreads();
#pragma unroll
    for (int cc = 0; cc < 16; ++cc) {
        const int c = cc * 4 + rq;
        const int gc = c0 + c;
        const int h = gc >> 6, d = gc & 63;
        Vt[((size_t)h * D_DIM + d) * T_LEN + t0 + cl] =
            __float2bfloat16(tile[cl][c]);
    }
}

__global__ __launch_bounds__(256) void proj_gemm(
    const float* __restrict__ x,
    const float* __restrict__ Wk, const float* __restrict__ bk,
    const float* __restrict__ Wq, const float* __restrict__ bq,
    __hip_bfloat16* __restrict__ kout, __hip_bfloat16* __restrict__ qout) {

    const float* W; const float* bias; __hip_bfloat16* out;
    float sc;
    if (blockIdx.z == 0) { W = Wk; bias = bk; out = kout; sc = LOG2E; }
    else                 { W = Wq; bias = bq; out = qout; sc = 1.0f; }

    __shared__ __align__(16) float As[32][68];
    __shared__ __align__(16) float Bs[32][68];

    const int tid = threadIdx.x;
    const int m0_blk = blockIdx.y * 64;
    const int n0_blk = blockIdx.x * 64;
    const int tx = tid & 15, ty = tid >> 4;
    const int mm = ty * 4, nn = tx * 4;
    float acc[4][4] = {};
    const int a_kq = tid & 7;
    const int a_m  = tid >> 3;
    const int b_n4 = (tid & 15) * 4;
    const int b_k  = tid >> 4;

    for (int k0 = 0; k0 < C_DIM; k0 += 32) {
#pragma unroll
        for (int half = 0; half < 2; ++half) {
            const int m = a_m + half * 32;
            const float4 av = *reinterpret_cast<const float4*>(
                &x[(size_t)(m0_blk + m) * C_DIM + k0 + a_kq * 4]);
            As[a_kq * 4 + 0][m] = av.x;
            As[a_kq * 4 + 1][m] = av.y;
            As[a_kq * 4 + 2][m] = av.z;
            As[a_kq * 4 + 3][m] = av.w;
        }
#pragma unroll
        for (int half = 0; half < 2; ++half) {
            const int kk = b_k + half * 16;
            *reinterpret_cast<float4*>(&Bs[kk][b_n4]) =
                *reinterpret_cast<const float4*>(
                    &W[(size_t)(k0 + kk) * C_DIM + n0_blk + b_n4]);
        }
        __syncthreads();
#pragma unroll
        for (int kk = 0; kk < 32; ++kk) {
            const float4 a4 = *reinterpret_cast<const float4*>(&As[kk][mm]);
            const float4 b4 = *reinterpret_cast<const float4*>(&Bs[kk][nn]);
            const float a_[4] = {a4.x, a4.y, a4.z, a4.w};
            const float b_[4] = {b4.x, b4.y, b4.z, b4.w};
#pragma unroll
            for (int i = 0; i < 4; ++i)
#pragma unroll
                for (int j = 0; j < 4; ++j)
                    acc[i][j] = fmaf(a_[i], b_[j], acc[i][j]);
        }
        __syncthreads();
    }

    const int h = blockIdx.x;
    const float4 bv = *reinterpret_cast<const float4*>(&bias[n0_blk + nn]);
    const float b_[4] = {bv.x, bv.y, bv.z, bv.w};
#pragma unroll
    for (int i = 0; i < 4; ++i) {
        const int t = m0_blk + mm + i;
        ushort4 o;
        o.x = bf16bits((acc[i][0] + b_[0]) * sc);
        o.y = bf16bits((acc[i][1] + b_[1]) * sc);
        o.z = bf16bits((acc[i][2] + b_[2]) * sc);
        o.w = bf16bits((acc[i][3] + b_[3]) * sc);
        *reinterpret_cast<ushort4*>(
            &out[((size_t)h * T_LEN + t) * D_DIM + nn]) = o;
    }
}

// ---------------------------------------------------------------------------
// LDS-staged split-j flash attention (round-10 validated structure),
// templated on SEGT = j-tiles per segment (32 = validated coarse; 16 = fine,
// 1728 blocks for 6.75 blocks/CU). exp2 domain (K pre-scaled by log2e).
// Slot = (h*PER_HEAD + ordinal)*4 + wave.
// ---------------------------------------------------------------------------
template <typename TP, int SEGT>
__global__ __launch_bounds__(256) void attn_split2(
    const __hip_bfloat16* __restrict__ K,   // [H][T][64] (log2e-scaled)
    const __hip_bfloat16* __restrict__ Q,   // [H][T][64]
    const __hip_bfloat16* __restrict__ Vt,  // [H][64][T]
    TP* __restrict__ pacc,
    float* __restrict__ pml) {

    constexpr int GDIV = SEGT / 4;
    constexpr int NGRP = 32 / GDIV;
    constexpr int PER_HEAD = GDIV * NGRP * (NGRP + 1) / 2;  // 144 (16) / 80 (32)
    constexpr int CHUNK = (12 * PER_HEAD) / 8;

    __shared__ __align__(16) char QsB[2][8192];
    __shared__ __align__(16) char VsB[2][8192];

    const int bid = blockIdx.x;
    const int wg  = (bid & 7) * CHUNK + (bid >> 3);   // XCD chunk swizzle
    const int hh  = wg / PER_HEAD;
    const int r   = PER_HEAD - 1 - (wg - hh * PER_HEAD);  // heavy-first
    int g = 0, base = 0;
    for (;;) {
        const int cnt = GDIV * (g + 1);
        if (r < base + cnt) break;
        base += cnt; ++g;
    }
    const int rem = r - base;
    const int ib  = g * GDIV + rem / (g + 1);
    const int s   = rem - (rem / (g + 1)) * (g + 1);

    const int tid  = threadIdx.x;
    const int wv   = tid >> 6;
    const int lane = tid & 63;
    const int lm   = lane & 31;
    const int hi   = lane >> 5;
    const int t    = ib * 4 + wv;
    const int iw   = t * 32;

    const int jt0  = s * SEGT;
    const int jend = min((s + 1) * SEGT, ib * 4 + 4);
    const int nsteps = (jend - jt0) >> 1;

    const __hip_bfloat16* kp = K + ((size_t)hh * T_LEN + iw + lm) * D_DIM + hi * 8;
    const bf16x8 bk0 = *reinterpret_cast<const bf16x8*>(kp + 0);
    const bf16x8 bk1 = *reinterpret_cast<const bf16x8*>(kp + 16);
    const bf16x8 bk2 = *reinterpret_cast<const bf16x8*>(kp + 32);
    const bf16x8 bk3 = *reinterpret_cast<const bf16x8*>(kp + 48);

    const __hip_bfloat16* qsc = Q  + ((size_t)hh * T_LEN + jt0 * 32) * D_DIM;
    const __hip_bfloat16* vsc = Vt + (size_t)hh * D_DIM * T_LEN + jt0 * 32;

    const int k0c = tid, k1c = tid + 256;
    const int lo0 = (k0c >> 3) * 128 + (((k0c & 7) ^ ((k0c >> 3) & 7)) << 4);
    const int lo1 = (k1c >> 3) * 128 + (((k1c & 7) ^ ((k1c >> 3) & 7)) << 4);
    const size_t vro0 = (size_t)(tid >> 3) * T_LEN + (tid & 7) * 8;
    const size_t vro1 = (size_t)((tid >> 3) + 32) * T_LEN + (tid & 7) * 8;

    uint4 rq0 = *reinterpret_cast<const uint4*>(qsc + (size_t)k0c * 8);
    uint4 rq1 = *reinterpret_cast<const uint4*>(qsc + (size_t)k1c * 8);
    uint4 rv0 = *reinterpret_cast<const uint4*>(vsc + vro0);
    uint4 rv1 = *reinterpret_cast<const uint4*>(vsc + vro1);
    *reinterpret_cast<uint4*>(QsB[0] + lo0) = rq0;
    *reinterpret_cast<uint4*>(QsB[0] + lo1) = rq1;
    *reinterpret_cast<uint4*>(VsB[0] + lo0) = rv0;
    *reinterpret_cast<uint4*>(VsB[0] + lo1) = rv1;
    __syncthreads();

    f32x16 acc0 = {}, acc1 = {};
    float m = -1e30f, lsum = 0.0f;

#define COMPUTE(SUB) do {                                                     \
    const int jt_ = jt0 + st * 2 + (SUB);                                     \
    if (jt_ <= t) {                                                           \
        const char* qb = QsB[cur];                                            \
        const char* vb = VsB[cur];                                            \
        const int qrow = (SUB) * 32 + lm;                                     \
        const int qsw = qrow & 7;                                             \
        const bf16x8 aq0 = *reinterpret_cast<const bf16x8*>(                  \
            qb + qrow * 128 + (((0 + hi) ^ qsw) << 4));                       \
        const bf16x8 aq1 = *reinterpret_cast<const bf16x8*>(                  \
            qb + qrow * 128 + (((2 + hi) ^ qsw) << 4));                       \
        const bf16x8 aq2 = *reinterpret_cast<const bf16x8*>(                  \
            qb + qrow * 128 + (((4 + hi) ^ qsw) << 4));                       \
        const bf16x8 aq3 = *reinterpret_cast<const bf16x8*>(                  \
            qb + qrow * 128 + (((6 + hi) ^ qsw) << 4));                       \
        f32x16 sc = {};                                                       \
        sc = __builtin_amdgcn_mfma_f32_32x32x16_bf16(aq0, bk0, sc, 0, 0, 0);  \
        sc = __builtin_amdgcn_mfma_f32_32x32x16_bf16(aq1, bk1, sc, 0, 0, 0);  \
        sc = __builtin_amdgcn_mfma_f32_32x32x16_bf16(aq2, bk2, sc, 0, 0, 0);  \
        sc = __builtin_amdgcn_mfma_f32_32x32x16_bf16(aq3, bk3, sc, 0, 0, 0);  \
        if (jt_ == t) {                                                       \
            _Pragma("unroll")                                                 \
            for (int rr = 0; rr < 16; ++rr) {                                 \
                const int jr = (rr & 3) + 8 * (rr >> 2) + 4 * hi;             \
                if (jr > lm) sc[rr] = -1e30f;                                 \
            }                                                                 \
        }                                                                     \
        float pmax = sc[0];                                                   \
        _Pragma("unroll")                                                     \
        for (int rr = 1; rr < 16; ++rr) pmax = fmaxf(pmax, sc[rr]);           \
        pmax = fmaxf(pmax, __shfl_xor(pmax, 32));                             \
        if (__any(pmax > m + 8.0f)) {                                         \
            const float mn = fmaxf(m, pmax);                                  \
            const float scl = exp2f(m - mn);                                  \
            lsum *= scl;                                                      \
            _Pragma("unroll")                                                 \
            for (int rr = 0; rr < 16; ++rr) {                                 \
                const float sr = __shfl(scl, (rr & 3) + 8 * (rr >> 2) + 4 * hi); \
                acc0[rr] *= sr;                                               \
                acc1[rr] *= sr;                                               \
            }                                                                 \
            m = mn;                                                           \
        }                                                                     \
        float p[16];                                                          \
        _Pragma("unroll")                                                     \
        for (int rr = 0; rr < 16; ++rr) p[rr] = exp2f(sc[rr] - m);            \
        float ls = 0.0f;                                                      \
        _Pragma("unroll")                                                     \
        for (int rr = 0; rr < 16; ++rr) ls += p[rr];                          \
        lsum += ls;                                                           \
        unsigned int w_[8];                                                   \
        _Pragma("unroll")                                                     \
        for (int kk = 0; kk < 8; ++kk)                                        \
            w_[kk] = (unsigned int)bf16bits(p[2 * kk]) |                      \
                     ((unsigned int)bf16bits(p[2 * kk + 1]) << 16);           \
        unsigned int pw_[8];                                                  \
        _Pragma("unroll")                                                     \
        for (int kk = 0; kk < 8; ++kk) pw_[kk] = __shfl_xor((int)w_[kk], 32); \
        const uint4 a0u = hi ? make_uint4(pw_[2], pw_[3], w_[2], w_[3])       \
                             : make_uint4(w_[0], w_[1], pw_[0], pw_[1]);      \
        const uint4 a1u = hi ? make_uint4(pw_[6], pw_[7], w_[6], w_[7])       \
                             : make_uint4(w_[4], w_[5], pw_[4], pw_[5]);      \
        const bf16x8 pa0 = __builtin_bit_cast(bf16x8, a0u);                   \
        const bf16x8 pa1 = __builtin_bit_cast(bf16x8, a1u);                   \
        const int d0 = lm, d1 = 32 + lm;                                      \
        const int vsw = lm & 7;                                               \
        const bf16x8 v00 = *reinterpret_cast<const bf16x8*>(                  \
            vb + d0 * 128 + ((((SUB) * 4 + 0 + hi) ^ vsw) << 4));             \
        const bf16x8 v01 = *reinterpret_cast<const bf16x8*>(                  \
            vb + d0 * 128 + ((((SUB) * 4 + 2 + hi) ^ vsw) << 4));             \
        const bf16x8 v10 = *reinterpret_cast<const bf16x8*>(                  \
            vb + d1 * 128 + ((((SUB) * 4 + 0 + hi) ^ vsw) << 4));             \
        const bf16x8 v11 = *reinterpret_cast<const bf16x8*>(                  \
            vb + d1 * 128 + ((((SUB) * 4 + 2 + hi) ^ vsw) << 4));             \
        acc0 = __builtin_amdgcn_mfma_f32_32x32x16_bf16(pa0, v00, acc0, 0,0,0);\
        acc0 = __builtin_amdgcn_mfma_f32_32x32x16_bf16(pa1, v01, acc0, 0,0,0);\
        acc1 = __builtin_amdgcn_mfma_f32_32x32x16_bf16(pa0, v10, acc1, 0,0,0);\
        acc1 = __builtin_amdgcn_mfma_f32_32x32x16_bf16(pa1, v11, acc1, 0,0,0);\
    }                                                                         \
} while (0)

    int cur = 0;
    for (int st = 0; st < nsteps; ++st) {
        const bool more = (st + 1 < nsteps);
        if (more) {
            rq0 = *reinterpret_cast<const uint4*>(qsc + (size_t)(st + 1) * 4096 + (size_t)k0c * 8);
            rq1 = *reinterpret_cast<const uint4*>(qsc + (size_t)(st + 1) * 4096 + (size_t)k1c * 8);
            rv0 = *reinterpret_cast<const uint4*>(vsc + vro0 + (size_t)(st + 1) * 64);
            rv1 = *reinterpret_cast<const uint4*>(vsc + vro1 + (size_t)(st + 1) * 64);
        }
        COMPUTE(0);
        COMPUTE(1);
        if (more) {
            char* qn = QsB[cur ^ 1];
            char* vn = VsB[cur ^ 1];
            *reinterpret_cast<uint4*>(qn + lo0) = rq0;
            *reinterpret_cast<uint4*>(qn + lo1) = rq1;
            *reinterpret_cast<uint4*>(vn + lo0) = rv0;
            *reinterpret_cast<uint4*>(vn + lo1) = rv1;
        }
        __syncthreads();
        cur ^= 1;
    }
#undef COMPUTE

    const int slot = (hh * PER_HEAD + r) * 4 + wv;
    const float lrow = lsum + __shfl_xor(lsum, 32);
    if (hi == 0) {
        pml[(size_t)slot * 64 + lm]      = m;
        pml[(size_t)slot * 64 + 32 + lm] = lrow;
    }
    TP* pa = pacc + (size_t)slot * 2048;
#pragma unroll
    for (int rr = 0; rr < 16; ++rr) {
        const int cr = (rr & 3) + 8 * (rr >> 2) + 4 * hi;
        stp(&pa[cr * 64 + lm],      acc0[rr]);
        stp(&pa[cr * 64 + 32 + lm], acc1[rr]);
    }
}

// ---------------------------------------------------------------------------
// Merge partials: slot = (h*PER_HEAD + bb(ib) + s)*4 + w, up to NGRP segs.
// ---------------------------------------------------------------------------
template <typename TP, int SEGT>
__global__ __launch_bounds__(256) void attn_merge(
    const TP* __restrict__ pacc, const float* __restrict__ pml,
    float* __restrict__ y) {
    constexpr int GDIV = SEGT / 4;
    constexpr int NGRP = 32 / GDIV;
    constexpr int PER_HEAD = GDIV * NGRP * (NGRP + 1) / 2;

    const int b = blockIdx.x;          // 1536
    const int h = b / 128;
    const int t = b - h * 128;
    const int ib = t >> 2, w = t & 3;
    const int g = ib / GDIV;
    const int ns = g + 1;
    const int bb = GDIV * g * (g + 1) / 2 + (ib % GDIV) * (g + 1);
    const int slot0 = (h * PER_HEAD + bb) * 4 + w;
    const int tid = threadIdx.x;
    const int row = tid >> 3;
    const int dq  = (tid & 7) * 8;

    float ms[NGRP], ls[NGRP];
#pragma unroll
    for (int si = 0; si < NGRP; ++si) {
        if (si < ns) {
            ms[si] = pml[(size_t)(slot0 + 4 * si) * 64 + row];
            ls[si] = pml[(size_t)(slot0 + 4 * si) * 64 + 32 + row];
        } else { ms[si] = -1e30f; ls[si] = 0.0f; }
    }
    float M = ms[0];
#pragma unroll
    for (int si = 1; si < NGRP; ++si) M = fmaxf(M, ms[si]);
    float wt_[NGRP];
    float L = 0.0f;
#pragma unroll
    for (int si = 0; si < NGRP; ++si) { wt_[si] = exp2f(ms[si] - M); L += ls[si] * wt_[si]; }
    const float inv = 1.0f / L;

    float o[8] = {};
#pragma unroll
    for (int si = 0; si < NGRP; ++si) {
        if (si < ns) {
            const TP* pa = pacc + (size_t)(slot0 + 4 * si) * 2048 + row * 64 + dq;
#pragma unroll
            for (int k = 0; k < 8; ++k) o[k] += ldp(&pa[k]) * wt_[si];
        }
    }
    float* yp = &y[(size_t)(t * 32 + row) * C_DIM + h * D_DIM + dq];
    float4 o0, o1;
    o0.x = o[0] * inv; o0.y = o[1] * inv; o0.z = o[2] * inv; o0.w = o[3] * inv;
    o1.x = o[4] * inv; o1.y = o[5] * inv; o1.z = o[6] * inv; o1.w = o[7] * inv;
    *reinterpret_cast<float4*>(yp + 0) = o0;
    *reinterpret_cast<float4*>(yp + 4) = o1;
}

// ---------------------------------------------------------------------------
// Flat attention fallback (exp2 domain): wave per (h, itile).
// ---------------------------------------------------------------------------
__global__ __launch_bounds__(256) void attn_flat(
    const __hip_bfloat16* __restrict__ K,
    const __hip_bfloat16* __restrict__ Q,
    const __hip_bfloat16* __restrict__ Vt,
    float* __restrict__ y) {

    const int u  = blockIdx.x * 4 + (threadIdx.x >> 6);
    const int h  = u % H_NUM;
    const int itile = (T_LEN / 32 - 1) - u / H_NUM;
    const int iw = itile * 32;
    const int lane = threadIdx.x & 63;
    const int lm = lane & 31;
    const int hi = lane >> 5;

    const __hip_bfloat16* kp = K + ((size_t)h * T_LEN + iw + lm) * D_DIM + hi * 8;
    const bf16x8 bk0 = *reinterpret_cast<const bf16x8*>(kp + 0);
    const bf16x8 bk1 = *reinterpret_cast<const bf16x8*>(kp + 16);
    const bf16x8 bk2 = *reinterpret_cast<const bf16x8*>(kp + 32);
    const bf16x8 bk3 = *reinterpret_cast<const bf16x8*>(kp + 48);

    f32x16 acc0 = {}, acc1 = {};
    float m = -1e30f, lsum = 0.0f;

    const __hip_bfloat16* qrow  = Q  + ((size_t)h * T_LEN + lm) * D_DIM + hi * 8;
    const __hip_bfloat16* vrow0 = Vt + ((size_t)h * D_DIM + lm) * T_LEN + hi * 8;
    const __hip_bfloat16* vrow1 = vrow0 + (size_t)32 * T_LEN;

    for (int j0 = 0; j0 <= iw; j0 += 32) {
        const __hip_bfloat16* qp = qrow + (size_t)j0 * D_DIM;
        const bf16x8 aq0 = *reinterpret_cast<const bf16x8*>(qp + 0);
        const bf16x8 aq1 = *reinterpret_cast<const bf16x8*>(qp + 16);
        const bf16x8 aq2 = *reinterpret_cast<const bf16x8*>(qp + 32);
        const bf16x8 aq3 = *reinterpret_cast<const bf16x8*>(qp + 48);

        f32x16 sc = {};
        sc = __builtin_amdgcn_mfma_f32_32x32x16_bf16(aq0, bk0, sc, 0, 0, 0);
        sc = __builtin_amdgcn_mfma_f32_32x32x16_bf16(aq1, bk1, sc, 0, 0, 0);
        sc = __builtin_amdgcn_mfma_f32_32x32x16_bf16(aq2, bk2, sc, 0, 0, 0);
        sc = __builtin_amdgcn_mfma_f32_32x32x16_bf16(aq3, bk3, sc, 0, 0, 0);

        if (j0 == iw) {
#pragma unroll
            for (int r = 0; r < 16; ++r) {
                const int jr = (r & 3) + 8 * (r >> 2) + 4 * hi;
                if (jr > lm) sc[r] = -1e30f;
            }
        }

        float pmax = sc[0];
#pragma unroll
        for (int r = 1; r < 16; ++r) pmax = fmaxf(pmax, sc[r]);
        pmax = fmaxf(pmax, __shfl_xor(pmax, 32));

        if (__any(pmax > m + 8.0f)) {
            const float mn = fmaxf(m, pmax);
            const float scl = exp2f(m - mn);
            lsum *= scl;
#pragma unroll
            for (int r = 0; r < 16; ++r) {
                const float sr = __shfl(scl, (r & 3) + 8 * (r >> 2) + 4 * hi);
                acc0[r] *= sr;
                acc1[r] *= sr;
            }
            m = mn;
        }

        float p[16];
#pragma unroll
        for (int r = 0; r < 16; ++r) p[r] = exp2f(sc[r] - m);
        float ls = 0.0f;
#pragma unroll
        for (int r = 0; r < 16; ++r) ls += p[r];
        lsum += ls;

        unsigned int w[8];
#pragma unroll
        for (int k = 0; k < 8; ++k)
            w[k] = (unsigned int)bf16bits(p[2 * k]) |
                   ((unsigned int)bf16bits(p[2 * k + 1]) << 16);
        unsigned int pw[8];
#pragma unroll
        for (int k = 0; k < 8; ++k) pw[k] = __shfl_xor((int)w[k], 32);

        const uint4 a0u = hi ? make_uint4(pw[2], pw[3], w[2], w[3])
                             : make_uint4(w[0], w[1], pw[0], pw[1]);
        const uint4 a1u = hi ? make_uint4(pw[6], pw[7], w[6], w[7])
                             : make_uint4(w[4], w[5], pw[4], pw[5]);
        const bf16x8 pa0 = __builtin_bit_cast(bf16x8, a0u);
        const bf16x8 pa1 = __builtin_bit_cast(bf16x8, a1u);

        const bf16x8 v00 = *reinterpret_cast<const bf16x8*>(vrow0 + j0);
        const bf16x8 v01 = *reinterpret_cast<const bf16x8*>(vrow0 + j0 + 16);
        const bf16x8 v10 = *reinterpret_cast<const bf16x8*>(vrow1 + j0);
        const bf16x8 v11 = *reinterpret_cast<const bf16x8*>(vrow1 + j0 + 16);

        acc0 = __builtin_amdgcn_mfma_f32_32x32x16_bf16(pa0, v00, acc0, 0, 0, 0);
        acc0 = __builtin_amdgcn_mfma_f32_32x32x16_bf16(pa1, v01, acc0, 0, 0, 0);
        acc1 = __builtin_amdgcn_mfma_f32_32x32x16_bf16(pa0, v10, acc1, 0, 0, 0);
        acc1 = __builtin_amdgcn_mfma_f32_32x32x16_bf16(pa1, v11, acc1, 0, 0, 0);
    }

    const float lt = lsum + __shfl_xor(lsum, 32);
    const float linv = 1.0f / lt;
#pragma unroll
    for (int r = 0; r < 16; ++r) {
        const int cr = (r & 3) + 8 * (r >> 2) + 4 * hi;
        const int row = iw + cr;
        const float li = __shfl(linv, cr);
        y[(size_t)row * C_DIM + h * D_DIM + lm]      = acc0[r] * li;
        y[(size_t)row * C_DIM + h * D_DIM + 32 + lm] = acc1[r] * li;
    }
}

// ---------------------------------------------------------------------------
extern "C" void kernel_launch(void* const* d_in, const int* in_sizes, int n_in,
                              void* d_out, int out_size, void* d_ws, size_t ws_size,
                              hipStream_t stream) {
    const float* x  = (const float*)d_in[0];
    const float* Wk = (const float*)d_in[1];
    const float* bk = (const float*)d_in[2];
    const float* Wq = (const float*)d_in[3];
    const float* bq = (const float*)d_in[4];
    float* out = (float*)d_out;

    const size_t np = (size_t)T_LEN * C_DIM;           // 3,145,728
    const size_t NSLOT_F = 12 * 144 * 4;               // 6912 (SEGT=16)
    const size_t NSLOT_C = 12 * 80 * 4;                // 3840 (SEGT=32)
    __hip_bfloat16* kbuf  = (__hip_bfloat16*)d_ws;     // [H][T][64] (log2e-scaled)
    __hip_bfloat16* qbuf  = kbuf + np;                 // [H][T][64]
    __hip_bfloat16* vtbuf = qbuf + np;                 // [H][64][T]
    char* after_kqv = (char*)(vtbuf + np);
    __hip_bfloat16* wtbuf = (__hip_bfloat16*)after_kqv;  // dead after proj

    const size_t wt_bytes  = 2 * (size_t)C_DIM * C_DIM * sizeof(__hip_bfloat16);
    const size_t base_b    = 3 * np * sizeof(__hip_bfloat16);
    const size_t needC     = base_b + wt_bytes;                                  // 21.2 MB
    const size_t needFineA = base_b + NSLOT_F * 2048 * 4 + NSLOT_F * 64 * 4;     // 77.3 MB
    const size_t needFineB = base_b + NSLOT_F * 2048 * 2 + NSLOT_F * 64 * 4;     // 49.0 MB
    const size_t needCoarB = base_b + NSLOT_C * 2048 * 2 + NSLOT_C * 64 * 4;     // 35.6 MB

    __hip_bfloat16* xhi = (__hip_bfloat16*)d_out;      // overlay d_out
    __hip_bfloat16* xlo = xhi + np;

    if (ws_size >= needC) {
        prep_kernel<<<1056, 256, 0, stream>>>(x, Wk, Wq, vtbuf, xhi, xlo, wtbuf);
        proj_mfma2<<<768, 256, 0, stream>>>(xhi, xlo, wtbuf, bk, bq, kbuf, qbuf);
    } else {
        dim3 gv(T_LEN / 64, C_DIM / 64);
        vtx_only_kernel<<<gv, 256, 0, stream>>>(x, vtbuf);
        dim3 g1(C_DIM / 64, T_LEN / 64, 2);
        proj_gemm<<<g1, 256, 0, stream>>>(x, Wk, bk, Wq, bq, kbuf, qbuf);
    }

    if (ws_size >= needFineA) {
        float* pacc = (float*)after_kqv;
        float* pml  = (float*)(after_kqv + NSLOT_F * 2048 * 4);
        attn_split2<float, 16><<<1728, 256, 0, stream>>>(kbuf, qbuf, vtbuf, pacc, pml);
        attn_merge<float, 16><<<1536, 256, 0, stream>>>(pacc, pml, out);
    } else if (ws_size >= needFineB) {
        __hip_bfloat16* pacc = (__hip_bfloat16*)after_kqv;
        float* pml = (float*)(after_kqv + NSLOT_F * 2048 * 2);
        attn_split2<__hip_bfloat16, 16><<<1728, 256, 0, stream>>>(kbuf, qbuf, vtbuf, pacc, pml);
        attn_merge<__hip_bfloat16, 16><<<1536, 256, 0, stream>>>(pacc, pml, out);
    } else if (ws_size >= needCoarB) {
        __hip_bfloat16* pacc = (__hip_bfloat16*)after_kqv;
        float* pml = (float*)(after_kqv + NSLOT_C * 2048 * 2);
        attn_split2<__hip_bfloat16, 32><<<960, 256, 0, stream>>>(kbuf, qbuf, vtbuf, pacc, pml);
        attn_merge<__hip_bfloat16, 32><<<1536, 256, 0, stream>>>(pacc, pml, out);
    } else {
        attn_flat<<<384, 256, 0, stream>>>(kbuf, qbuf, vtbuf, out);
    }
}